// Round 11
// baseline (109.612 us; speedup 1.0000x reference)
//
#include <hip/hip_runtime.h>

// Problem constants (B=2, L=16, D=4, K=2, N_IN=8, N_OUT=8, NC=3)
#define NSITES (2 * 16 * 16 * 16 * 16)          // 131072 sites
// W:     site-stride 72  floats (8 ch * 3*3), base 288 B (16B aligned)
// U_PT:  site-stride 180 floats (4 mu * 5 ik * 3*3)
// omega: flat [i][j][mu][ik] = i*160 + j*20 + mu*5 + ik  (1280 floats)
// out:   site-stride 72 floats
//
// R11 = R10 + cross-ik register software pipeline for W.
//   Per thread (8 thr/site = (jh,mu)): A[5] f4 = floats 0..19 of its 36-float
//   half, loaded ONE ik AHEAD (t=0,t=1 channels + floats 18,19 of ch2);
//   B[4] f4 = floats 20..35, loaded at iteration top, first used at t=2
//   (~430 cyc of compute cover). Every loaded f4 is fully consumed.
//   U_PT + omega staged in LDS once per block (R9/R10).

#define OM_OFF 0                 // 4*328 = 1312 floats
#define U_OFF  1312              // 32*184 = 5888 floats
#define LDS_FLOATS (U_OFF + 5888)   // 7200 floats = 28800 B

// sandwich channel T (9 row-major floats) + omega-mix into acc
#define DO_CH(T, w0,w1,w2,w3,w4,w5,w6,w7,w8) do {                           \
    float M[9];                                                             \
    _Pragma("unroll")                                                       \
    for (int a = 0; a < 3; ++a) {                                           \
        const float uw0 = fmaf(U[a*3+0], (w0),                              \
                          fmaf(U[a*3+1], (w3), U[a*3+2] * (w6)));           \
        const float uw1 = fmaf(U[a*3+0], (w1),                              \
                          fmaf(U[a*3+1], (w4), U[a*3+2] * (w7)));           \
        const float uw2 = fmaf(U[a*3+0], (w2),                              \
                          fmaf(U[a*3+1], (w5), U[a*3+2] * (w8)));           \
        _Pragma("unroll")                                                   \
        for (int b2 = 0; b2 < 3; ++b2)                                      \
            M[a*3+b2] = fmaf(uw0, U[b2*3+0],                                \
                        fmaf(uw1, U[b2*3+1], uw2 * U[b2*3+2]));             \
    }                                                                       \
    const float4 wo = *reinterpret_cast<const float4*>(                     \
                          omt + ik * 64 + jown8 + (T) * 8);                 \
    const float4 wp = *reinterpret_cast<const float4*>(                     \
                          omt + ik * 64 + jpar8 + (T) * 8);                 \
    const float wov[4] = {wo.x, wo.y, wo.z, wo.w};                          \
    const float wpv[4] = {wp.x, wp.y, wp.z, wp.w};                          \
    _Pragma("unroll")                                                       \
    for (int e = 0; e < 9; ++e) {                                           \
        const float mp = __shfl_xor(M[e], 4);                               \
        _Pragma("unroll")                                                   \
        for (int ii = 0; ii < 4; ++ii)                                      \
            acc[ii][e] = fmaf(wov[ii], M[e], fmaf(wpv[ii], mp, acc[ii][e]));\
    }                                                                       \
} while (0)

__global__ __launch_bounds__(256) void lconv_kernel(
    const float* __restrict__ W, const float* __restrict__ U_PT,
    const float* __restrict__ omega, float* __restrict__ out)
{
    __shared__ float lds[LDS_FLOATS];
    const int tid = threadIdx.x;

    // XCD-aware bijective swizzle: 4096 blocks, 8 XCDs, 512-block chunks.
    const int bid = ((int)blockIdx.x & 7) * ((int)gridDim.x >> 3)
                  + ((int)blockIdx.x >> 3);
    const int s0  = bid * 32;

    // ---- one-time staging ----
    {
        const int site = tid >> 3;       // 0..31
        const int r8   = tid & 7;        // 0..7

        // omega -> [mu][ik][j][i] (1280 floats)
        for (int t = tid; t < 1280; t += 256) {
            const int i  = t / 160;
            const int r  = t - i * 160;
            const int j  = r / 20;
            const int r2 = r - j * 20;
            const int m  = r2 / 5;
            const int ik = r2 - m * 5;
            lds[OM_OFF + m * 328 + ik * 64 + j * 8 + i] = omega[t];
        }

        // U slice: 32 sites x 45 float4 -> [site][184] (lane-linear, coalesced)
        const float4* __restrict__ U4 =
            reinterpret_cast<const float4*>(U_PT) + (size_t)s0 * 45;
#pragma unroll
        for (int st = 0; st < 6; ++st) {
            const int f4r = st * 8 + r8;
            if (st < 5 || f4r < 45) {
                *reinterpret_cast<float4*>(
                    lds + U_OFF + site * 184 + f4r * 4) =
                    U4[site * 45 + f4r];
            }
        }
    }
    __syncthreads();

    const int local = tid >> 3;          // 0..31 site local id
    const int s     = s0 + local;
    const int jh    = (tid >> 2) & 1;    // j-half AND i-half
    const int mu    = tid & 3;           // axis
    const int sh    = 12 - 4 * mu;       // bit position of x_mu in s
    const int x     = (s >> sh) & 15;

    const float* __restrict__ Ul  = lds + U_OFF + local * 184 + mu * 45;
    const float* __restrict__ omt = lds + OM_OFF + mu * 328 + jh * 4;
    const int jown8 = jh * 32;
    const int jpar8 = (jh ^ 1) * 32;

    float acc[4][9];
#pragma unroll
    for (int i = 0; i < 4; ++i)
#pragma unroll
        for (int e = 0; e < 9; ++e) acc[i][e] = 0.0f;

    // neighbor half-block base for shift k
    const float* base0 = W + (size_t)s * 72 + jh * 36;
#define NBASE(kk) reinterpret_cast<const float4*>( \
        base0 + ((((((x + (kk) + 16) & 15) - x)) << sh) * 72))

    // ---- prologue: A = f4 0..4 of ik=0 (k=-2) ----
    const float4* pcur = NBASE(-2);
    float4 A0 = pcur[0], A1 = pcur[1], A2 = pcur[2], A3 = pcur[3], A4 = pcur[4];

#pragma unroll 1
    for (int ik = 0; ik < 5; ++ik) {
        const int kn = ((ik < 4) ? ik + 1 : ik) - 2;   // next-ik shift (clamped)
        const float4* pnext = NBASE(kn);

        // U for this ik from LDS (fast, issued first)
        float U[9];
#pragma unroll
        for (int e = 0; e < 9; ++e) U[e] = Ul[ik * 9 + e];

        // B: rest of current half (f4 5..8), used at t=2 -> ~430cyc cover
        const float4 B0 = pcur[5], B1 = pcur[6], B2 = pcur[7], B3 = pcur[8];
        // N: next ik's f4 0..4, used next iteration -> ~1000cyc cover
        const float4 N0 = pnext[0], N1 = pnext[1], N2 = pnext[2],
                     N3 = pnext[3], N4 = pnext[4];

        // channel floats (row-major 3x3 each):
        // ch0 = f0-8, ch1 = f9-17, ch2 = f18-26, ch3 = f27-35
        DO_CH(0, A0.x, A0.y, A0.z, A0.w, A1.x, A1.y, A1.z, A1.w, A2.x);
        DO_CH(1, A2.y, A2.z, A2.w, A3.x, A3.y, A3.z, A3.w, A4.x, A4.y);
        DO_CH(2, A4.z, A4.w, B0.x, B0.y, B0.z, B0.w, B1.x, B1.y, B1.z);
        DO_CH(3, B1.w, B2.x, B2.y, B2.z, B2.w, B3.x, B3.y, B3.z, B3.w);

        // rotate pipeline
        A0 = N0; A1 = N1; A2 = N2; A3 = N3; A4 = N4;
        pcur = pnext;
    }

    // reduce the 4 mu-partials within each mu-quad
#pragma unroll
    for (int i = 0; i < 4; ++i)
#pragma unroll
        for (int e = 0; e < 9; ++e) {
            float v = acc[i][e];
            v += __shfl_xor(v, 1);
            v += __shfl_xor(v, 2);
            acc[i][e] = v;
        }

    // mu==0 lanes (2 per site) store their 36-float half-block (9 float4)
    if (mu == 0) {
        float4* __restrict__ o4 =
            reinterpret_cast<float4*>(out + (size_t)s * 72 + jh * 36);
#pragma unroll
        for (int q = 0; q < 9; ++q) {
            const int f = q * 4;
            o4[q] = make_float4(acc[(f + 0) / 9][(f + 0) % 9],
                                acc[(f + 1) / 9][(f + 1) % 9],
                                acc[(f + 2) / 9][(f + 2) % 9],
                                acc[(f + 3) / 9][(f + 3) % 9]);
        }
    }
}

extern "C" void kernel_launch(void* const* d_in, const int* in_sizes, int n_in,
                              void* d_out, int out_size, void* d_ws, size_t ws_size,
                              hipStream_t stream) {
    const float* W   = (const float*)d_in[0];
    const float* U   = (const float*)d_in[1];
    const float* om  = (const float*)d_in[2];
    float*       out = (float*)d_out;

    const int block = 256;
    const int grid  = NSITES / 32;    // 4096 blocks, 32 sites each
    hipLaunchKernelGGL(lconv_kernel, dim3(grid), dim3(block), 0, stream,
                       W, U, om, out);
}